// Round 3
// baseline (101.336 us; speedup 1.0000x reference)
//
#include <hip/hip_runtime.h>

#define HIDDEN   1024
#define NEXP     8
#define NTOK     32768           // 4 * 8192
#define TOK_PER_WAVE 8
#define WAVES_PER_BLOCK 4
#define NBLOCKS  (NTOK / (TOK_PER_WAVE * WAVES_PER_BLOCK))   // 1024

// Full 64-lane reduction of 8 per-lane partial sums.
// Returns, in every lane, the fully reduced value for expert (lane & 7).
// (Bit-identical to the passing round-1/2 version.)
__device__ __forceinline__ float split_reduce8(const float (&acc)[8], int lane) {
    float a4[4];
    {
        const bool hi = (lane & 4) != 0;
        #pragma unroll
        for (int j = 0; j < 4; ++j) {
            float send = hi ? acc[j] : acc[j + 4];
            float recv = __shfl_xor(send, 4, 64);
            a4[j] = (hi ? acc[j + 4] : acc[j]) + recv;
        }
    }
    float a2[2];
    {
        const bool hi = (lane & 2) != 0;
        #pragma unroll
        for (int j = 0; j < 2; ++j) {
            float snd = hi ? a4[j] : a4[j + 2];
            float recv = __shfl_xor(snd, 2, 64);
            a2[j] = (hi ? a4[j + 2] : a4[j]) + recv;
        }
    }
    float a1;
    {
        const bool hi = (lane & 1) != 0;
        float send = hi ? a2[0] : a2[1];
        float recv = __shfl_xor(send, 1, 64);
        a1 = (hi ? a2[1] : a2[0]) + recv;
    }
    a1 += __shfl_xor(a1, 8, 64);
    a1 += __shfl_xor(a1, 16, 64);
    a1 += __shfl_xor(a1, 32, 64);
    return a1;
}

// Per-lane-group softmax+top2. selv = this lane-group's token logit for
// expert (lane&7), replicated per group. 8-lane groups alternate token0/token1.
__device__ __forceinline__ void softmax_top2_lane(float selv, int lane,
                                                  float& w1, float& w2,
                                                  int& i1, int& i2, float& myp) {
    const int gbase = lane & 56;
    float l[8];
    #pragma unroll
    for (int e = 0; e < 8; ++e) l[e] = __shfl(selv, gbase + e, 64);
    float m = l[0];
    #pragma unroll
    for (int e = 1; e < 8; ++e) m = fmaxf(m, l[e]);
    float p[8];
    float s = 0.f;
    #pragma unroll
    for (int e = 0; e < 8; ++e) { p[e] = __expf(l[e] - m); s += p[e]; }
    const float inv = 1.f / s;

    i1 = 0; float v1 = p[0];
    #pragma unroll
    for (int e = 1; e < 8; ++e) { if (p[e] > v1) { v1 = p[e]; i1 = e; } }
    i2 = -1; float v2 = -1.f;
    #pragma unroll
    for (int e = 0; e < 8; ++e) { if (e != i1 && p[e] > v2) { v2 = p[e]; i2 = e; } }

    const float wsum = v1 + v2;
    w1 = v1 / wsum;
    w2 = v2 / wsum;
    myp = p[lane & 7] * inv;
}

__device__ __forceinline__ void load_pair(const float4* __restrict__ h4,
                                          size_t tok, int lane,
                                          float4 (&h0)[4], float4 (&h1)[4]) {
    const size_t base = tok * 256;   // 256 float4 per row
    #pragma unroll
    for (int j = 0; j < 4; ++j) h0[j] = h4[base + j * 64 + lane];
    #pragma unroll
    for (int j = 0; j < 4; ++j) h1[j] = h4[base + 256 + j * 64 + lane];
}

__device__ __forceinline__ void process_pair(const float4 (&h0)[4], const float4 (&h1)[4],
                                             const float4 (&Wf)[8][4],
                                             int lane, int t0,
                                             float* __restrict__ out_w,
                                             float* __restrict__ out_sel,
                                             float& ps_acc, unsigned* s_cnt) {
    float acc0[8], acc1[8];
    #pragma unroll
    for (int e = 0; e < 8; ++e) {
        float a = 0.f, c = 0.f;
        #pragma unroll
        for (int j = 0; j < 4; ++j) {
            a = fmaf(h0[j].x, Wf[e][j].x, a);
            a = fmaf(h0[j].y, Wf[e][j].y, a);
            a = fmaf(h0[j].z, Wf[e][j].z, a);
            a = fmaf(h0[j].w, Wf[e][j].w, a);
            c = fmaf(h1[j].x, Wf[e][j].x, c);
            c = fmaf(h1[j].y, Wf[e][j].y, c);
            c = fmaf(h1[j].z, Wf[e][j].z, c);
            c = fmaf(h1[j].w, Wf[e][j].w, c);
        }
        acc0[e] = a; acc1[e] = c;
    }

    const float r0 = split_reduce8(acc0, lane);
    const float r1 = split_reduce8(acc1, lane);

    const int tokSel = (lane >> 3) & 1;      // 8-lane groups alternate tokens
    const float selv = tokSel ? r1 : r0;

    float w1, w2, myp; int i1, i2;
    softmax_top2_lane(selv, lane, w1, w2, i1, i2, myp);

    // lanes 0-15 own aux prob accumulation (expert lane&7, token lane>>3)
    ps_acc += myp;

    // expert-count: lanes 0,1 (token0 i1,i2) and 8,9 (token1 i1,i2)
    if ((lane & 54) == 0)
        atomicAdd(&s_cnt[(lane & 1) ? i2 : i1], 1u);

    // writes: lane 0 -> token t0, lane 8 -> token t0+1
    if ((lane & 55) == 0) {
        const int t = t0 + tokSel;
        ((float2*)out_w)[t]   = make_float2(w1, w2);
        ((float2*)out_sel)[t] = make_float2((float)i1, (float)i2);
    }
}

__global__ __launch_bounds__(256, 4)
void moe_router_kernel(const float* __restrict__ h, const float* __restrict__ wg,
                       float* __restrict__ out_w, float* __restrict__ out_sel,
                       float* __restrict__ ws) {
    __shared__ float    s_ps[8];
    __shared__ unsigned s_cnt[8];
    const int tid  = threadIdx.x;
    const int lane = tid & 63;
    const int widx = tid >> 6;

    if (tid < 8) { s_ps[tid] = 0.f; s_cnt[tid] = 0u; }
    __syncthreads();

    const float4* wg4 = (const float4*)wg;
    float4 Wf[8][4];
    #pragma unroll
    for (int e = 0; e < 8; ++e)
        #pragma unroll
        for (int j = 0; j < 4; ++j)
            Wf[e][j] = wg4[e * 256 + j * 64 + lane];

    const int gw      = blockIdx.x * WAVES_PER_BLOCK + widx;
    const int tokBase = gw * TOK_PER_WAVE;
    const float4* h4  = (const float4*)h;
    float ps_acc = 0.f;

    float4 hA0[4], hA1[4], hB0[4], hB1[4];
    load_pair(h4, (size_t)tokBase, lane, hA0, hA1);

    #pragma unroll
    for (int bb = 0; bb < TOK_PER_WAVE / 4; ++bb) {
        const int tA = tokBase + 4 * bb;
        const int tB = tA + 2;
        load_pair(h4, (size_t)tB, lane, hB0, hB1);                 // prefetch B
        process_pair(hA0, hA1, Wf, lane, tA, out_w, out_sel, ps_acc, s_cnt);
        if (bb < TOK_PER_WAVE / 4 - 1)
            load_pair(h4, (size_t)(tA + 4), lane, hA0, hA1);       // prefetch next A
        process_pair(hB0, hB1, Wf, lane, tB, out_w, out_sel, ps_acc, s_cnt);
    }

    if (lane < 16) atomicAdd(&s_ps[lane & 7], ps_acc);
    __syncthreads();

    if (tid < 8) {
        ws[(size_t)blockIdx.x * 16 + tid]     = s_ps[tid];
        ws[(size_t)blockIdx.x * 16 + 8 + tid] = (float)s_cnt[tid];  // exact (<=64)
    }
}

__global__ void moe_finalize_kernel(const float* __restrict__ ws,
                                    float* __restrict__ aux_out) {
    __shared__ float s[256];
    const int t     = threadIdx.x;
    const int col   = t & 15;     // 0-7: ps_e, 8-15: cnt_e
    const int chunk = t >> 4;     // 16 chunks x 64 blocks
    float acc = 0.f;
    #pragma unroll 4
    for (int b = chunk * 64; b < chunk * 64 + 64; ++b)
        acc += ws[(size_t)b * 16 + col];
    s[t] = acc;
    __syncthreads();
    if (t < 16) {
        float v = 0.f;
        #pragma unroll
        for (int c = 0; c < 16; ++c) v += s[c * 16 + t];
        s[t] = v;
    }
    __syncthreads();
    if (t == 0) {
        const float invT = 1.0f / (float)NTOK;
        float a = 0.f;
        #pragma unroll
        for (int e = 0; e < 8; ++e)
            a += (s[8 + e] * invT) * (s[e] * invT);
        *aux_out = (float)NEXP * a;
    }
}

extern "C" void kernel_launch(void* const* d_in, const int* in_sizes, int n_in,
                              void* d_out, int out_size, void* d_ws, size_t ws_size,
                              hipStream_t stream) {
    const float* h  = (const float*)d_in[0];   // [4, 8192, 1024] f32
    const float* wg = (const float*)d_in[1];   // [8, 1024] f32

    float* out_w   = (float*)d_out;            // [4,8192,2,1] -> 65536
    float* out_sel = out_w + 65536;            // [4,8192,2]   -> 65536 (as float)
    float* aux     = out_w + 131072;           // scalar

    float* ws = (float*)d_ws;                  // 1024 blocks x 16 floats (written every call)

    moe_router_kernel<<<NBLOCKS, 256, 0, stream>>>(h, wg, out_w, out_sel, ws);
    moe_finalize_kernel<<<1, 256, 0, stream>>>(ws, aux);
}

// Round 4
// 36.268 us; speedup vs baseline: 2.7941x; 2.7941x over previous
//
#include <hip/hip_runtime.h>

#define HIDDEN   1024
#define NEXP     8
#define NTOK     32768           // 4 * 8192
#define TOK_PER_WAVE 8
#define WAVES_PER_BLOCK 4
#define NBLOCKS  (NTOK / (TOK_PER_WAVE * WAVES_PER_BLOCK))   // 1024

// Full 64-lane reduction of 8 per-lane partial sums.
// Returns, in every lane, the fully reduced value for expert (lane & 7).
// (Bit-identical to the passing round-1/2 version.)
__device__ __forceinline__ float split_reduce8(const float (&acc)[8], int lane) {
    float a4[4];
    {
        const bool hi = (lane & 4) != 0;
        #pragma unroll
        for (int j = 0; j < 4; ++j) {
            float send = hi ? acc[j] : acc[j + 4];
            float recv = __shfl_xor(send, 4, 64);
            a4[j] = (hi ? acc[j + 4] : acc[j]) + recv;
        }
    }
    float a2[2];
    {
        const bool hi = (lane & 2) != 0;
        #pragma unroll
        for (int j = 0; j < 2; ++j) {
            float snd = hi ? a4[j] : a4[j + 2];
            float recv = __shfl_xor(snd, 2, 64);
            a2[j] = (hi ? a4[j + 2] : a4[j]) + recv;
        }
    }
    float a1;
    {
        const bool hi = (lane & 1) != 0;
        float send = hi ? a2[0] : a2[1];
        float recv = __shfl_xor(send, 1, 64);
        a1 = (hi ? a2[1] : a2[0]) + recv;
    }
    a1 += __shfl_xor(a1, 8, 64);
    a1 += __shfl_xor(a1, 16, 64);
    a1 += __shfl_xor(a1, 32, 64);
    return a1;
}

// Per-lane-group softmax+top2. selv = this lane-group's token logit for
// expert (lane&7), replicated per group. 8-lane groups alternate token0/token1.
__device__ __forceinline__ void softmax_top2_lane(float selv, int lane,
                                                  float& w1, float& w2,
                                                  int& i1, int& i2, float& myp) {
    const int gbase = lane & 56;
    float l[8];
    #pragma unroll
    for (int e = 0; e < 8; ++e) l[e] = __shfl(selv, gbase + e, 64);
    float m = l[0];
    #pragma unroll
    for (int e = 1; e < 8; ++e) m = fmaxf(m, l[e]);
    float p[8];
    float s = 0.f;
    #pragma unroll
    for (int e = 0; e < 8; ++e) { p[e] = __expf(l[e] - m); s += p[e]; }
    const float inv = 1.f / s;

    i1 = 0; float v1 = p[0];
    #pragma unroll
    for (int e = 1; e < 8; ++e) { if (p[e] > v1) { v1 = p[e]; i1 = e; } }
    i2 = -1; float v2 = -1.f;
    #pragma unroll
    for (int e = 0; e < 8; ++e) { if (e != i1 && p[e] > v2) { v2 = p[e]; i2 = e; } }

    const float wsum = v1 + v2;
    w1 = v1 / wsum;
    w2 = v2 / wsum;
    myp = p[lane & 7] * inv;
}

__device__ __forceinline__ void load_pair(const float4* __restrict__ h4,
                                          size_t tok, int lane,
                                          float4 (&h0)[4], float4 (&h1)[4]) {
    const size_t base = tok * 256;   // 256 float4 per row
    #pragma unroll
    for (int j = 0; j < 4; ++j) h0[j] = h4[base + j * 64 + lane];
    #pragma unroll
    for (int j = 0; j < 4; ++j) h1[j] = h4[base + 256 + j * 64 + lane];
}

__device__ __forceinline__ void process_pair(const float4 (&h0)[4], const float4 (&h1)[4],
                                             const float4 (&Wf)[8][4],
                                             int lane, int t0,
                                             float* __restrict__ out_w,
                                             float* __restrict__ out_sel,
                                             float& ps_acc, unsigned* s_cnt) {
    float acc0[8], acc1[8];
    #pragma unroll
    for (int e = 0; e < 8; ++e) {
        float a = 0.f, c = 0.f;
        #pragma unroll
        for (int j = 0; j < 4; ++j) {
            a = fmaf(h0[j].x, Wf[e][j].x, a);
            a = fmaf(h0[j].y, Wf[e][j].y, a);
            a = fmaf(h0[j].z, Wf[e][j].z, a);
            a = fmaf(h0[j].w, Wf[e][j].w, a);
            c = fmaf(h1[j].x, Wf[e][j].x, c);
            c = fmaf(h1[j].y, Wf[e][j].y, c);
            c = fmaf(h1[j].z, Wf[e][j].z, c);
            c = fmaf(h1[j].w, Wf[e][j].w, c);
        }
        acc0[e] = a; acc1[e] = c;
    }

    const float r0 = split_reduce8(acc0, lane);
    const float r1 = split_reduce8(acc1, lane);

    const int tokSel = (lane >> 3) & 1;      // 8-lane groups alternate tokens
    const float selv = tokSel ? r1 : r0;

    float w1, w2, myp; int i1, i2;
    softmax_top2_lane(selv, lane, w1, w2, i1, i2, myp);

    // lanes 0-15 own aux prob accumulation (expert lane&7, token lane>>3)
    ps_acc += myp;

    // expert-count: lanes 0,1 (token0 i1,i2) and 8,9 (token1 i1,i2)
    if ((lane & 54) == 0)
        atomicAdd(&s_cnt[(lane & 1) ? i2 : i1], 1u);

    // writes: lane 0 -> token t0, lane 8 -> token t0+1
    if ((lane & 55) == 0) {
        const int t = t0 + tokSel;
        ((float2*)out_w)[t]   = make_float2(w1, w2);
        ((float2*)out_sel)[t] = make_float2((float)i1, (float)i2);
    }
}

// launch_bounds(256,2): proven to compile at 128 VGPR with zero scratch
// (round 2). (256,4) forced a 64-VGPR target -> 122 MB of spill traffic
// and a 3.5x regression (round 3). HW still co-schedules 4 waves/SIMD at
// 128 VGPR, so occupancy comes from the 1024-block grid, not this bound.
__global__ __launch_bounds__(256, 2)
void moe_router_kernel(const float* __restrict__ h, const float* __restrict__ wg,
                       float* __restrict__ out_w, float* __restrict__ out_sel,
                       float* __restrict__ ws) {
    __shared__ float    s_ps[8];
    __shared__ unsigned s_cnt[8];
    const int tid  = threadIdx.x;
    const int lane = tid & 63;
    const int widx = tid >> 6;

    if (tid < 8) { s_ps[tid] = 0.f; s_cnt[tid] = 0u; }
    __syncthreads();

    const float4* wg4 = (const float4*)wg;
    float4 Wf[8][4];
    #pragma unroll
    for (int e = 0; e < 8; ++e)
        #pragma unroll
        for (int j = 0; j < 4; ++j)
            Wf[e][j] = wg4[e * 256 + j * 64 + lane];

    const int gw      = blockIdx.x * WAVES_PER_BLOCK + widx;
    const int tokBase = gw * TOK_PER_WAVE;
    const float4* h4  = (const float4*)h;
    float ps_acc = 0.f;

    float4 hA0[4], hA1[4], hB0[4], hB1[4];
    load_pair(h4, (size_t)tokBase, lane, hA0, hA1);

    #pragma unroll
    for (int bb = 0; bb < TOK_PER_WAVE / 4; ++bb) {
        const int tA = tokBase + 4 * bb;
        const int tB = tA + 2;
        load_pair(h4, (size_t)tB, lane, hB0, hB1);                 // prefetch B
        process_pair(hA0, hA1, Wf, lane, tA, out_w, out_sel, ps_acc, s_cnt);
        if (bb < TOK_PER_WAVE / 4 - 1)
            load_pair(h4, (size_t)(tA + 4), lane, hA0, hA1);       // prefetch next A
        process_pair(hB0, hB1, Wf, lane, tB, out_w, out_sel, ps_acc, s_cnt);
    }

    if (lane < 16) atomicAdd(&s_ps[lane & 7], ps_acc);
    __syncthreads();

    if (tid < 8) {
        ws[(size_t)blockIdx.x * 16 + tid]     = s_ps[tid];
        ws[(size_t)blockIdx.x * 16 + 8 + tid] = (float)s_cnt[tid];  // exact (<=64)
    }
}

__global__ void moe_finalize_kernel(const float* __restrict__ ws,
                                    float* __restrict__ aux_out) {
    __shared__ float s[256];
    const int t     = threadIdx.x;
    const int col   = t & 15;     // 0-7: ps_e, 8-15: cnt_e
    const int chunk = t >> 4;     // 16 chunks x 64 blocks
    float acc = 0.f;
    #pragma unroll 4
    for (int b = chunk * 64; b < chunk * 64 + 64; ++b)
        acc += ws[(size_t)b * 16 + col];
    s[t] = acc;
    __syncthreads();
    if (t < 16) {
        float v = 0.f;
        #pragma unroll
        for (int c = 0; c < 16; ++c) v += s[c * 16 + t];
        s[t] = v;
    }
    __syncthreads();
    if (t == 0) {
        const float invT = 1.0f / (float)NTOK;
        float a = 0.f;
        #pragma unroll
        for (int e = 0; e < 8; ++e)
            a += (s[8 + e] * invT) * (s[e] * invT);
        *aux_out = (float)NEXP * a;
    }
}

extern "C" void kernel_launch(void* const* d_in, const int* in_sizes, int n_in,
                              void* d_out, int out_size, void* d_ws, size_t ws_size,
                              hipStream_t stream) {
    const float* h  = (const float*)d_in[0];   // [4, 8192, 1024] f32
    const float* wg = (const float*)d_in[1];   // [8, 1024] f32

    float* out_w   = (float*)d_out;            // [4,8192,2,1] -> 65536
    float* out_sel = out_w + 65536;            // [4,8192,2]   -> 65536 (as float)
    float* aux     = out_w + 131072;           // scalar

    float* ws = (float*)d_ws;                  // 1024 blocks x 16 floats (written every call)

    moe_router_kernel<<<NBLOCKS, 256, 0, stream>>>(h, wg, out_w, out_sel, ws);
    moe_finalize_kernel<<<1, 256, 0, stream>>>(ws, aux);
}

// Round 5
// 33.900 us; speedup vs baseline: 2.9893x; 1.0698x over previous
//
#include <hip/hip_runtime.h>

#define HIDDEN   1024
#define NEXP     8
#define NTOK     32768           // 4 * 8192
#define TOK_PER_WAVE 8
#define WAVES_PER_BLOCK 4
#define NBLOCKS  (NTOK / (TOK_PER_WAVE * WAVES_PER_BLOCK))   // 1024

// Full 64-lane reduction of 8 per-lane partial sums.
// Returns, in every lane, the fully reduced value for expert (lane & 7).
// (Bit-identical to the passing round-1/2/4 version.)
__device__ __forceinline__ float split_reduce8(const float (&acc)[8], int lane) {
    float a4[4];
    {
        const bool hi = (lane & 4) != 0;
        #pragma unroll
        for (int j = 0; j < 4; ++j) {
            float send = hi ? acc[j] : acc[j + 4];
            float recv = __shfl_xor(send, 4, 64);
            a4[j] = (hi ? acc[j + 4] : acc[j]) + recv;
        }
    }
    float a2[2];
    {
        const bool hi = (lane & 2) != 0;
        #pragma unroll
        for (int j = 0; j < 2; ++j) {
            float snd = hi ? a4[j] : a4[j + 2];
            float recv = __shfl_xor(snd, 2, 64);
            a2[j] = (hi ? a4[j + 2] : a4[j]) + recv;
        }
    }
    float a1;
    {
        const bool hi = (lane & 1) != 0;
        float send = hi ? a2[0] : a2[1];
        float recv = __shfl_xor(send, 1, 64);
        a1 = (hi ? a2[1] : a2[0]) + recv;
    }
    a1 += __shfl_xor(a1, 8, 64);
    a1 += __shfl_xor(a1, 16, 64);
    a1 += __shfl_xor(a1, 32, 64);
    return a1;
}

// Per-lane-group softmax+top2. selv = this lane-group's token logit for
// expert (lane&7), replicated per group. 8-lane groups alternate token0/token1.
__device__ __forceinline__ void softmax_top2_lane(float selv, int lane,
                                                  float& w1, float& w2,
                                                  int& i1, int& i2, float& myp) {
    const int gbase = lane & 56;
    float l[8];
    #pragma unroll
    for (int e = 0; e < 8; ++e) l[e] = __shfl(selv, gbase + e, 64);
    float m = l[0];
    #pragma unroll
    for (int e = 1; e < 8; ++e) m = fmaxf(m, l[e]);
    float p[8];
    float s = 0.f;
    #pragma unroll
    for (int e = 0; e < 8; ++e) { p[e] = __expf(l[e] - m); s += p[e]; }
    const float inv = 1.f / s;

    i1 = 0; float v1 = p[0];
    #pragma unroll
    for (int e = 1; e < 8; ++e) { if (p[e] > v1) { v1 = p[e]; i1 = e; } }
    i2 = -1; float v2 = -1.f;
    #pragma unroll
    for (int e = 0; e < 8; ++e) { if (e != i1 && p[e] > v2) { v2 = p[e]; i2 = e; } }

    const float wsum = v1 + v2;
    w1 = v1 / wsum;
    w2 = v2 / wsum;
    myp = p[lane & 7] * inv;
}

__device__ __forceinline__ void load_pair(const float4* __restrict__ h4,
                                          size_t tok, int lane,
                                          float4 (&h0)[4], float4 (&h1)[4]) {
    const size_t base = tok * 256;   // 256 float4 per row
    #pragma unroll
    for (int j = 0; j < 4; ++j) h0[j] = h4[base + j * 64 + lane];
    #pragma unroll
    for (int j = 0; j < 4; ++j) h1[j] = h4[base + 256 + j * 64 + lane];
}

__device__ __forceinline__ void process_pair(const float4 (&h0)[4], const float4 (&h1)[4],
                                             const float4 (&Wf)[8][4],
                                             int lane, int t0,
                                             float* __restrict__ out_w,
                                             float* __restrict__ out_sel,
                                             float& ps_acc, unsigned* s_cnt) {
    float acc0[8], acc1[8];
    #pragma unroll
    for (int e = 0; e < 8; ++e) {
        float a = 0.f, c = 0.f;
        #pragma unroll
        for (int j = 0; j < 4; ++j) {
            a = fmaf(h0[j].x, Wf[e][j].x, a);
            a = fmaf(h0[j].y, Wf[e][j].y, a);
            a = fmaf(h0[j].z, Wf[e][j].z, a);
            a = fmaf(h0[j].w, Wf[e][j].w, a);
            c = fmaf(h1[j].x, Wf[e][j].x, c);
            c = fmaf(h1[j].y, Wf[e][j].y, c);
            c = fmaf(h1[j].z, Wf[e][j].z, c);
            c = fmaf(h1[j].w, Wf[e][j].w, c);
        }
        acc0[e] = a; acc1[e] = c;
    }

    const float r0 = split_reduce8(acc0, lane);
    const float r1 = split_reduce8(acc1, lane);

    const int tokSel = (lane >> 3) & 1;      // 8-lane groups alternate tokens
    const float selv = tokSel ? r1 : r0;

    float w1, w2, myp; int i1, i2;
    softmax_top2_lane(selv, lane, w1, w2, i1, i2, myp);

    // lanes 0-15 own aux prob accumulation (expert lane&7, token lane>>3)
    ps_acc += myp;

    // expert-count: lanes 0,1 (token0 i1,i2) and 8,9 (token1 i1,i2)
    if ((lane & 54) == 0)
        atomicAdd(&s_cnt[(lane & 1) ? i2 : i1], 1u);

    // writes: lane 0 -> token t0, lane 8 -> token t0+1
    if ((lane & 55) == 0) {
        const int t = t0 + tokSel;
        ((float2*)out_w)[t]   = make_float2(w1, w2);
        ((float2*)out_sel)[t] = make_float2((float)i1, (float)i2);
    }
}

// launch_bounds: max-threads only. Round 3 proved that a min-waves arg of 4
// forces a 64-VGPR target -> 122 MB spill traffic. Here we WANT ~230 VGPR so
// the W fragments stay resident (see asm pin below).
__global__ __launch_bounds__(256)
void moe_router_kernel(const float* __restrict__ h, const float* __restrict__ wg,
                       float* __restrict__ out_w, float* __restrict__ out_sel,
                       float* __restrict__ ws) {
    __shared__ float    s_ps[8];
    __shared__ unsigned s_cnt[8];
    const int tid  = threadIdx.x;
    const int lane = tid & 63;
    const int widx = tid >> 6;

    if (tid < 8) { s_ps[tid] = 0.f; s_cnt[tid] = 0u; }
    __syncthreads();

    const float4* wg4 = (const float4*)wg;
    float4 Wf[8][4];
    #pragma unroll
    for (int e = 0; e < 8; ++e)
        #pragma unroll
        for (int j = 0; j < 4; ++j)
            Wf[e][j] = wg4[e * 256 + j * 64 + lane];

    // Pin W in VGPRs: opaque asm defs make rematerialization (per-pair
    // global reloads of W, seen in round 2: VGPR_Count=128 despite a
    // 128-float W tile) impossible. Inner loop becomes a pure h-stream.
    #pragma unroll
    for (int e = 0; e < 8; ++e)
        #pragma unroll
        for (int j = 0; j < 4; ++j)
            asm volatile("" : "+v"(Wf[e][j].x), "+v"(Wf[e][j].y),
                              "+v"(Wf[e][j].z), "+v"(Wf[e][j].w));

    const int gw      = blockIdx.x * WAVES_PER_BLOCK + widx;
    const int tokBase = gw * TOK_PER_WAVE;
    const float4* h4  = (const float4*)h;
    float ps_acc = 0.f;

    float4 hA0[4], hA1[4], hB0[4], hB1[4];
    load_pair(h4, (size_t)tokBase, lane, hA0, hA1);

    #pragma unroll
    for (int bb = 0; bb < TOK_PER_WAVE / 4; ++bb) {
        const int tA = tokBase + 4 * bb;
        const int tB = tA + 2;
        load_pair(h4, (size_t)tB, lane, hB0, hB1);                 // prefetch B
        process_pair(hA0, hA1, Wf, lane, tA, out_w, out_sel, ps_acc, s_cnt);
        if (bb < TOK_PER_WAVE / 4 - 1)
            load_pair(h4, (size_t)(tA + 4), lane, hA0, hA1);       // prefetch next A
        process_pair(hB0, hB1, Wf, lane, tB, out_w, out_sel, ps_acc, s_cnt);
    }

    if (lane < 16) atomicAdd(&s_ps[lane & 7], ps_acc);
    __syncthreads();

    // ws layout: [16][NBLOCKS] so finalize reads coalesced float4.
    if (tid < 8) {
        ws[(size_t)tid * NBLOCKS + blockIdx.x]       = s_ps[tid];
        ws[(size_t)(tid + 8) * NBLOCKS + blockIdx.x] = (float)s_cnt[tid];  // exact (<=64)
    }
}

__global__ void moe_finalize_kernel(const float* __restrict__ ws,
                                    float* __restrict__ aux_out) {
    __shared__ float s[256];
    const int t = threadIdx.x;
    const int k = t >> 4;         // 0-7: ps_e, 8-15: cnt_e
    const int j = t & 15;         // 16 threads per k
    const float4* w4 = (const float4*)(ws + (size_t)k * NBLOCKS);  // 256 float4 per k
    float acc = 0.f;
    #pragma unroll
    for (int i = 0; i < 16; ++i) {
        float4 v = w4[j + i * 16];
        acc += v.x + v.y + v.z + v.w;
    }
    s[t] = acc;
    __syncthreads();
    if (t < 16) {
        float v = 0.f;
        #pragma unroll
        for (int c = 0; c < 16; ++c) v += s[t * 16 + c];
        s[t] = v;
    }
    __syncthreads();
    if (t == 0) {
        const float invT = 1.0f / (float)NTOK;
        float a = 0.f;
        #pragma unroll
        for (int e = 0; e < 8; ++e)
            a += (s[8 + e] * invT) * (s[e] * invT);
        *aux_out = (float)NEXP * a;
    }
}

extern "C" void kernel_launch(void* const* d_in, const int* in_sizes, int n_in,
                              void* d_out, int out_size, void* d_ws, size_t ws_size,
                              hipStream_t stream) {
    const float* h  = (const float*)d_in[0];   // [4, 8192, 1024] f32
    const float* wg = (const float*)d_in[1];   // [8, 1024] f32

    float* out_w   = (float*)d_out;            // [4,8192,2,1] -> 65536
    float* out_sel = out_w + 65536;            // [4,8192,2]   -> 65536 (as float)
    float* aux     = out_w + 131072;           // scalar

    float* ws = (float*)d_ws;                  // [16][1024] floats (fully rewritten every call)

    moe_router_kernel<<<NBLOCKS, 256, 0, stream>>>(h, wg, out_w, out_sel, ws);
    moe_finalize_kernel<<<1, 256, 0, stream>>>(ws, aux);
}